// Round 11
// baseline (134.652 us; speedup 1.0000x reference)
//
#include <hip/hip_runtime.h>
#include <cstdint>

// Problem constants: features (B=4, C=256, H=64, W=64) fp32,
// rois (N=2000, 5) fp32, output (N, C, 7, 7) fp32.
constexpr int CCH = 256;
constexpr int HH  = 64;
constexpr int WW  = 64;
constexpr int OHW = 49;
constexpr float RSCALE = 0.0625f;

// Bit-exact fp32 ops on the coordinate path (xs<64 validity test is the only
// discontinuity in the op).
#define FMUL __fmul_rn
#define FADD __fadd_rn
#define FSUB __fsub_rn
#define FDIV __fdiv_rn

typedef float v4f __attribute__((ext_vector_type(4)));

__device__ __forceinline__ float4 f4max(float4 a, float4 b) {
  return make_float4(fmaxf(a.x, b.x), fmaxf(a.y, b.y),
                     fmaxf(a.z, b.z), fmaxf(a.w, b.w));
}

__device__ __forceinline__ unsigned short f2bf(float f) {   // RNE f32->bf16
  union { float f; unsigned u; } a; a.f = f;
  unsigned u = a.u;
  u += 0x7fffu + ((u >> 16) & 1u);
  return (unsigned short)(u >> 16);
}

__device__ __forceinline__ float4 bf4_to_f4(uint2 u) {      // 4 bf16 -> 4 f32
  float4 r;
  r.x = __uint_as_float(u.x << 16);
  r.y = __uint_as_float(u.x & 0xffff0000u);
  r.z = __uint_as_float(u.y << 16);
  r.w = __uint_as_float(u.y & 0xffff0000u);
  return r;
}

// ---------------------------------------------------------------------------
// Kernel 1 (fused): transpose+quantize features (B,C,H*W) f32 -> (B,H*W,C)
// bf16, PLUS the roi scheduling pass as one extra grid slice (z==B, block
// (0,0)). Transpose reads non-temporal (use-once fp32).
// Scheduling (XCD-batch affinity, 4 blocks/roi): roi block i -> XCD i%8
// (round-robin heuristic); pair p=(i&7)>>1 gets batch-p rois so each XCD's
// gather set is one 2.1 MB slice (< 4 MiB XCD L2).
// Within-pair task w=(i>>3)*2+(i&1); roi slot sr=w>>2; quarter q=w&3.
// meta: [0..3]=cnt [4..7]=off [8..11]=cumslack; perm[N]; extra[N].
// ---------------------------------------------------------------------------
__global__ __launch_bounds__(256) void ktrans_sched(const float* __restrict__ in,
                                                    unsigned short* __restrict__ out,
                                                    const float* __restrict__ rois,
                                                    int N, int slots, int do_sched,
                                                    int B, int* __restrict__ meta) {
  const int t = threadIdx.x;

  if ((int)blockIdx.z == B) {
    if (blockIdx.x != 0 || blockIdx.y != 0 || !do_sched) return;
    __shared__ int cnt[4], rnk[4], off[4], slack[4], excess[4];
    if (t < 4) { cnt[t] = 0; rnk[t] = 0; }
    __syncthreads();
    for (int i = t; i < N; i += 256) atomicAdd(&cnt[(int)rois[i * 5]], 1);
    __syncthreads();
    if (t == 0) {
      int o = 0, cs = 0, ce = 0;
      for (int p = 0; p < 4; ++p) {
        off[p] = o; o += cnt[p];
        slack[p]  = cs; if (slots - cnt[p] > 0) cs += slots - cnt[p];
        excess[p] = ce; if (cnt[p] - slots > 0) ce += cnt[p] - slots;
        meta[p] = cnt[p]; meta[4 + p] = off[p]; meta[8 + p] = slack[p];
      }
    }
    __syncthreads();
    int* perm = meta + 16;
    for (int i = t; i < N; i += 256) {
      const int b = (int)rois[i * 5];
      perm[off[b] + atomicAdd(&rnk[b], 1)] = i;
    }
    __syncthreads();
    int* extra = meta + 16 + N;
    for (int p = 0; p < 4; ++p) {
      const int ex = cnt[p] - slots;
      for (int e = t; e < ex; e += 256) extra[excess[p] + e] = perm[off[p] + slots + e];
    }
    return;
  }

  __shared__ float tile[64][65];
  const int b  = blockIdx.z;
  const int c0 = blockIdx.y * 64;
  const int s0 = blockIdx.x * 64;
  const float* inb = in + (size_t)b * CCH * (HH * WW);
  unsigned short* outb = out + (size_t)b * (HH * WW) * CCH;

  const int cl = t >> 4, sq = t & 15;
#pragma unroll
  for (int k = 0; k < 4; ++k) {
    const int c = cl + 16 * k;
    const v4f v = __builtin_nontemporal_load(
        (const v4f*)(inb + (size_t)(c0 + c) * (HH * WW) + s0 + 4 * sq));
    tile[c][4 * sq + 0] = v[0];
    tile[c][4 * sq + 1] = v[1];
    tile[c][4 * sq + 2] = v[2];
    tile[c][4 * sq + 3] = v[3];
  }
  __syncthreads();
  const int cq = t & 15, rl = t >> 4;
#pragma unroll
  for (int k = 0; k < 4; ++k) {
    const int r = rl + 16 * k;
    ushort4 w;
    w.x = f2bf(tile[4 * cq + 0][r]);
    w.y = f2bf(tile[4 * cq + 1][r]);
    w.z = f2bf(tile[4 * cq + 2][r]);
    w.w = f2bf(tile[4 * cq + 3][r]);
    *(ushort4*)(outb + (size_t)(s0 + r) * CCH + c0 + 4 * cq) = w;
  }
}

// ---------------------------------------------------------------------------
// Kernel 2: RoIAlign + 2x2 s1 maxpool, v9. FOUR blocks per roi (channel
// quarters, 64 ch each), 128 threads = 2 waves. Thread t: g=t&15 -> granule
// (4 channels of this quarter), r=t>>4 -> sample row 0..7.
// LDS [49][16] float4 = 12544 B -> 12 blocks/CU (vs v8's 6): 2x more
// independent gather/exchange/writeback phase streams per CU to keep the
// store pipe continuously fed (r10 showed roi ~8 us over its 15.6 us write
// floor; theory: bursty per-block phases).
// __launch_bounds__ arg2 = min WORKGROUPS/CU (measured r5); (128,12) ->
// 24 waves/CU -> VGPR cap ~85, same as the no-spill r8 config.
// ---------------------------------------------------------------------------
__global__ __launch_bounds__(128, 12) void roi_kernel9(const uint2* __restrict__ feat,
                                                       const float* __restrict__ rois,
                                                       const int* __restrict__ meta,
                                                       int N, int use_perm,
                                                       float* __restrict__ out) {
  __shared__ float4 smem4[OHW * 16];           // 12544 B, two aliased phases
  float* smem = (float*)smem4;
  const int i = blockIdx.x;
  const int t = threadIdx.x;
  const int g = t & 15;                        // granule within quarter
  const int r = t >> 4;                        // sample row 0..7

  int n, quarter;
  if (use_perm) {
    const int p  = (i & 7) >> 1;
    const int w  = ((i >> 3) << 1) | (i & 1); // within-pair task index
    const int sr = w >> 2;                    // roi slot in pair
    quarter      = w & 3;
    const int c_ = meta[p];
    const int o_ = meta[4 + p];
    const int sl = meta[8 + p];
    const int* perm  = meta + 16;
    const int* extra = meta + 16 + N;
    n = (sr < c_) ? perm[o_ + sr] : extra[sl + (sr - c_)];
  } else {
    n = i >> 2; quarter = i & 3;
  }

  const float rb = rois[n * 5 + 0];
  const float x1 = FMUL(rois[n * 5 + 1], RSCALE);
  const float y1 = FMUL(rois[n * 5 + 2], RSCALE);
  const float x2 = FMUL(rois[n * 5 + 3], RSCALE);
  const float y2 = FMUL(rois[n * 5 + 4], RSCALE);
  const int   b  = (int)rb;
  const float bh = FDIV(FSUB(y2, y1), 7.0f);
  const float bw = FDIV(FSUB(x2, x1), 7.0f);

  int   xo0[8], xo1[8];
  float lx[8];
  bool  xv[8];
#pragma unroll
  for (int q = 0; q < 8; ++q) {
    const float xs = FADD(x1, FMUL(bw, (float)q));
    xv[q] = (xs >= 0.0f) && (xs < (float)WW);
    const float xf = floorf(xs);
    lx[q] = FSUB(xs, xf);
    int a = (int)xf;
    a = a < 0 ? 0 : (a > WW - 1 ? WW - 1 : a);
    xo0[q] = a * (CCH / 4);
    xo1[q] = ((a + 1 > WW - 1) ? WW - 1 : a + 1) * (CCH / 4);
  }

  const float ys = FADD(y1, FMUL(bh, (float)r));
  const bool  yv = (ys >= 0.0f) && (ys < (float)HH);
  const float yf = floorf(ys);
  const float ly = FSUB(ys, yf);
  int d = (int)yf;
  d = d < 0 ? 0 : (d > HH - 1 ? HH - 1 : d);
  const int d1 = (d + 1 > HH - 1) ? HH - 1 : d + 1;

  const uint2* fb = feat + (size_t)b * (HH * WW) * (CCH / 4) + (quarter * 16 + g);
  const uint2* r0 = fb + (size_t)d  * (WW * (CCH / 4));
  const uint2* r1 = fb + (size_t)d1 * (WW * (CCH / 4));
  const float wy1 = ly, wy0 = 1.0f - ly;

  float4 hc[7], vprev;
#pragma unroll
  for (int h = 0; h < 2; ++h) {
    uint2 g00[4], g01[4], g10[4], g11[4];
#pragma unroll
    for (int q = 0; q < 4; ++q) {              // 16 independent loads in flight
      const int s = 4 * h + q;
      g00[q] = r0[xo0[s]];
      g01[q] = r0[xo1[s]];
      g10[q] = r1[xo0[s]];
      g11[q] = r1[xo1[s]];
    }
    float4 v[4];
#pragma unroll
    for (int q = 0; q < 4; ++q) {
      const int s = 4 * h + q;
      const bool ok = yv && xv[s];
      const float wx1 = lx[s], wx0 = 1.0f - wx1;
      const float a00 = wy0 * wx0, a01 = wy0 * wx1;
      const float a10 = wy1 * wx0, a11 = wy1 * wx1;
      const float4 f00 = bf4_to_f4(g00[q]);
      const float4 f01 = bf4_to_f4(g01[q]);
      const float4 f10 = bf4_to_f4(g10[q]);
      const float4 f11 = bf4_to_f4(g11[q]);
      float4 rr;
      rr.x = a00 * f00.x + a01 * f01.x + a10 * f10.x + a11 * f11.x;
      rr.y = a00 * f00.y + a01 * f01.y + a10 * f10.y + a11 * f11.y;
      rr.z = a00 * f00.z + a01 * f01.z + a10 * f10.z + a11 * f11.z;
      rr.w = a00 * f00.w + a01 * f01.w + a10 * f10.w + a11 * f11.w;
      v[q] = ok ? rr : make_float4(0.f, 0.f, 0.f, 0.f);
    }
    if (h == 0) {
      hc[0] = f4max(v[0], v[1]);
      hc[1] = f4max(v[1], v[2]);
      hc[2] = f4max(v[2], v[3]);
      vprev = v[3];
    } else {
      hc[3] = f4max(vprev, v[0]);
      hc[4] = f4max(v[0], v[1]);
      hc[5] = f4max(v[1], v[2]);
      hc[6] = f4max(v[2], v[3]);
    }
  }

  // ---- exchange hc rows: row r>=1 publishes at slot r-1 ----
  if (r >= 1) {
#pragma unroll
    for (int m = 0; m < 7; ++m)
      smem4[((r - 1) * 7 + m) * 16 + g] = hc[m];
  }
  __syncthreads();

  // ---- vertical max: row r<=6 reads row r+1's hc -> output row r ----
  if (r <= 6) {
#pragma unroll
    for (int m = 0; m < 7; ++m)
      hc[m] = f4max(hc[m], smem4[(r * 7 + m) * 16 + g]);
  }
  __syncthreads();

  // ---- stage output row r (same LDS, swizzled channel-minor) ----
  if (r <= 6) {
#pragma unroll
    for (int m = 0; m < 7; ++m) {
      const int s  = r * 7 + m;
      const int gp = g ^ ((s >> 2) & 7);       // XOR swizzle (4-bit granule)
      smem4[s * 16 + gp] = hc[m];
    }
  }
  __syncthreads();

  // ---- cached float4 writeback: 784 float4 over 128 threads ----
  float4* o4 = (float4*)(out + (size_t)n * (CCH * OHW) + quarter * (CCH / 4) * OHW);
#pragma unroll
  for (int m = 0; m < 7; ++m) {
    const int idx = m * 128 + t;
    if (idx < (CCH / 4) * OHW / 4) {
      const int f0 = idx * 4;
      float4 wv;
      float* wp = (float*)&wv;
#pragma unroll
      for (int k = 0; k < 4; ++k) {
        const int e = f0 + k;
        const int c = e / 49;                  // local channel 0..63
        const int s = e - c * 49;
        wp[k] = smem[s * 64 + 4 * ((c >> 2) ^ ((s >> 2) & 7)) + (c & 3)];
      }
      o4[idx] = wv;
    }
  }
}

// ---------------------------------------------------------------------------
// Fallback (workspace too small): round-2 scalar path, known-correct.
// ---------------------------------------------------------------------------
__global__ __launch_bounds__(256) void roi_kernel_fb(const float* __restrict__ feat,
                                                     const float* __restrict__ rois,
                                                     float* __restrict__ out) {
  __shared__ float sout[CCH * OHW];
  const int n = blockIdx.x;
  const int c = threadIdx.x;

  const float rb = rois[n * 5 + 0];
  const float x1 = FMUL(rois[n * 5 + 1], RSCALE);
  const float y1 = FMUL(rois[n * 5 + 2], RSCALE);
  const float x2 = FMUL(rois[n * 5 + 3], RSCALE);
  const float y2 = FMUL(rois[n * 5 + 4], RSCALE);
  const int b = (int)rb;
  const float bh = FDIV(FSUB(y2, y1), 7.0f);
  const float bw = FDIV(FSUB(x2, x1), 7.0f);

  int ix0[8], ix1[8], iy0[8], iy1[8];
  float lx[8], ly[8];
  bool xv[8], yv[8];
#pragma unroll
  for (int i = 0; i < 8; ++i) {
    const float xs = FADD(x1, FMUL(bw, (float)i));
    const float ys = FADD(y1, FMUL(bh, (float)i));
    xv[i] = (xs >= 0.0f) && (xs < (float)WW);
    yv[i] = (ys >= 0.0f) && (ys < (float)HH);
    const float xf = floorf(xs);
    const float yf = floorf(ys);
    lx[i] = FSUB(xs, xf);
    ly[i] = FSUB(ys, yf);
    int a = (int)xf;
    a = a < 0 ? 0 : (a > WW - 1 ? WW - 1 : a);
    ix0[i] = a;
    ix1[i] = (a + 1 > WW - 1) ? WW - 1 : a + 1;
    int d = (int)yf;
    d = d < 0 ? 0 : (d > HH - 1 ? HH - 1 : d);
    iy0[i] = d;
    iy1[i] = (d + 1 > HH - 1) ? HH - 1 : d + 1;
  }

  const float* fbp = feat + ((size_t)b * CCH + c) * (size_t)(HH * WW);
  float hp[7];
#pragma unroll
  for (int j = 0; j < 8; ++j) {
    float v[8];
    const float wy1 = ly[j], wy0 = 1.0f - ly[j];
#pragma unroll
    for (int i = 0; i < 8; ++i) {
      if (yv[j] && xv[i]) {
        const float f00 = fbp[iy0[j] * WW + ix0[i]];
        const float f01 = fbp[iy0[j] * WW + ix1[i]];
        const float f10 = fbp[iy1[j] * WW + ix0[i]];
        const float f11 = fbp[iy1[j] * WW + ix1[i]];
        const float wx1 = lx[i], wx0 = 1.0f - wx1;
        v[i] = wy0 * (wx0 * f00 + wx1 * f01) + wy1 * (wx0 * f10 + wx1 * f11);
      } else {
        v[i] = 0.0f;
      }
    }
    float hc[7];
#pragma unroll
    for (int i = 0; i < 7; ++i) hc[i] = fmaxf(v[i], v[i + 1]);
    if (j > 0) {
#pragma unroll
      for (int i = 0; i < 7; ++i)
        sout[c * OHW + (j - 1) * 7 + i] = fmaxf(hp[i], hc[i]);
    }
#pragma unroll
    for (int i = 0; i < 7; ++i) hp[i] = hc[i];
  }
  __syncthreads();
  const float4* s4 = (const float4*)sout;
  float4* o4 = (float4*)(out + (size_t)n * (CCH * OHW));
  for (int q = c; q < (CCH * OHW) / 4; q += 256) o4[q] = s4[q];
}

extern "C" void kernel_launch(void* const* d_in, const int* in_sizes, int n_in,
                              void* d_out, int out_size, void* d_ws, size_t ws_size,
                              hipStream_t stream) {
  (void)n_in; (void)out_size;
  const float* feat = (const float*)d_in[0];
  const float* rois = (const float*)d_in[1];
  float* out = (float*)d_out;
  const int N = in_sizes[1] / 5;
  const int B = in_sizes[0] / (CCH * HH * WW);
  const int M = 4 * N;                                  // roi blocks (4/roi)
  const size_t featbf_bytes = (size_t)in_sizes[0] * sizeof(unsigned short);
  const size_t meta_bytes   = (size_t)(16 + 2 * N) * sizeof(int);

  if (ws_size >= featbf_bytes + meta_bytes) {
    unsigned short* featbf = (unsigned short*)d_ws;
    int* meta = (int*)((char*)d_ws + featbf_bytes);
    // Need M divisible by 16 so each XCD-pair gets integral roi slots.
    const int use_perm = (B == 4 && (M & 15) == 0) ? 1 : 0;

    ktrans_sched<<<dim3((HH * WW) / 64, CCH / 64, B + 1), dim3(256), 0, stream>>>(
        feat, featbf, rois, N, M >> 4, use_perm, B, meta);
    roi_kernel9<<<dim3(M), dim3(128), 0, stream>>>(
        (const uint2*)featbf, rois, meta, N, use_perm, out);
  } else {
    roi_kernel_fb<<<dim3(N), dim3(256), 0, stream>>>(feat, rois, out);
  }
}

// Round 12
// 133.565 us; speedup vs baseline: 1.0081x; 1.0081x over previous
//
#include <hip/hip_runtime.h>
#include <cstdint>

// Problem constants: features (B=4, C=256, H=64, W=64) fp32,
// rois (N=2000, 5) fp32, output (N, C, 7, 7) fp32.
constexpr int CCH = 256;
constexpr int HH  = 64;
constexpr int WW  = 64;
constexpr int OHW = 49;
constexpr float RSCALE = 0.0625f;

// Bit-exact fp32 ops on the coordinate path (xs<64 validity test is the only
// discontinuity in the op).
#define FMUL __fmul_rn
#define FADD __fadd_rn
#define FSUB __fsub_rn
#define FDIV __fdiv_rn

typedef float v4f __attribute__((ext_vector_type(4)));

__device__ __forceinline__ float4 f4max(float4 a, float4 b) {
  return make_float4(fmaxf(a.x, b.x), fmaxf(a.y, b.y),
                     fmaxf(a.z, b.z), fmaxf(a.w, b.w));
}

__device__ __forceinline__ unsigned short f2bf(float f) {   // RNE f32->bf16
  union { float f; unsigned u; } a; a.f = f;
  unsigned u = a.u;
  u += 0x7fffu + ((u >> 16) & 1u);
  return (unsigned short)(u >> 16);
}

__device__ __forceinline__ float4 bf4_to_f4(uint2 u) {      // 4 bf16 -> 4 f32
  float4 r;
  r.x = __uint_as_float(u.x << 16);
  r.y = __uint_as_float(u.x & 0xffff0000u);
  r.z = __uint_as_float(u.y << 16);
  r.w = __uint_as_float(u.y & 0xffff0000u);
  return r;
}

// ---------------------------------------------------------------------------
// Kernel 1 (fused): transpose+quantize features (B,C,H*W) f32 -> (B,H*W,C)
// bf16, PLUS the roi scheduling pass as one extra grid slice (z==B, block
// (0,0)). Transpose reads non-temporal (use-once fp32).
// Scheduling (XCD-batch affinity, 2 blocks/roi): roi block i -> XCD i%8
// (round-robin heuristic); pair p=(i&7)>>1 gets batch-p rois so each XCD's
// gather set is one 2.1 MB slice (< 4 MiB XCD L2). slot s=i>>3.
// meta: [0..3]=cnt [4..7]=off [8..11]=cumslack; perm[N]; extra[N].
// ---------------------------------------------------------------------------
__global__ __launch_bounds__(256) void ktrans_sched(const float* __restrict__ in,
                                                    unsigned short* __restrict__ out,
                                                    const float* __restrict__ rois,
                                                    int N, int slots, int do_sched,
                                                    int B, int* __restrict__ meta) {
  const int t = threadIdx.x;

  if ((int)blockIdx.z == B) {
    if (blockIdx.x != 0 || blockIdx.y != 0 || !do_sched) return;
    __shared__ int cnt[4], rnk[4], off[4], slack[4], excess[4];
    if (t < 4) { cnt[t] = 0; rnk[t] = 0; }
    __syncthreads();
    for (int i = t; i < N; i += 256) atomicAdd(&cnt[(int)rois[i * 5]], 1);
    __syncthreads();
    if (t == 0) {
      int o = 0, cs = 0, ce = 0;
      for (int p = 0; p < 4; ++p) {
        off[p] = o; o += cnt[p];
        slack[p]  = cs; if (slots - cnt[p] > 0) cs += slots - cnt[p];
        excess[p] = ce; if (cnt[p] - slots > 0) ce += cnt[p] - slots;
        meta[p] = cnt[p]; meta[4 + p] = off[p]; meta[8 + p] = slack[p];
      }
    }
    __syncthreads();
    int* perm = meta + 16;
    for (int i = t; i < N; i += 256) {
      const int b = (int)rois[i * 5];
      perm[off[b] + atomicAdd(&rnk[b], 1)] = i;
    }
    __syncthreads();
    int* extra = meta + 16 + N;
    for (int p = 0; p < 4; ++p) {
      const int ex = cnt[p] - slots;
      for (int e = t; e < ex; e += 256) extra[excess[p] + e] = perm[off[p] + slots + e];
    }
    return;
  }

  __shared__ float tile[64][65];
  const int b  = blockIdx.z;
  const int c0 = blockIdx.y * 64;
  const int s0 = blockIdx.x * 64;
  const float* inb = in + (size_t)b * CCH * (HH * WW);
  unsigned short* outb = out + (size_t)b * (HH * WW) * CCH;

  const int cl = t >> 4, sq = t & 15;
#pragma unroll
  for (int k = 0; k < 4; ++k) {
    const int c = cl + 16 * k;
    const v4f v = __builtin_nontemporal_load(
        (const v4f*)(inb + (size_t)(c0 + c) * (HH * WW) + s0 + 4 * sq));
    tile[c][4 * sq + 0] = v[0];
    tile[c][4 * sq + 1] = v[1];
    tile[c][4 * sq + 2] = v[2];
    tile[c][4 * sq + 3] = v[3];
  }
  __syncthreads();
  const int cq = t & 15, rl = t >> 4;
#pragma unroll
  for (int k = 0; k < 4; ++k) {
    const int r = rl + 16 * k;
    ushort4 w;
    w.x = f2bf(tile[4 * cq + 0][r]);
    w.y = f2bf(tile[4 * cq + 1][r]);
    w.z = f2bf(tile[4 * cq + 2][r]);
    w.w = f2bf(tile[4 * cq + 3][r]);
    *(ushort4*)(outb + (size_t)(s0 + r) * CCH + c0 + 4 * cq) = w;
  }
}

// ---------------------------------------------------------------------------
// Kernel 2: RoIAlign + 2x2 s1 maxpool. Best-measured r10 variant (2 blocks
// per roi, 256 threads, cached writeback) with the middle barrier removed
// (3 -> 2 __syncthreads per block). Proof of legality: for slot (row r, m,
// gx) the phase-B reader is thread (gx,r) and the phase-C writer is thread
// (gx^swz,r) — same 32-thread row-group, same wave, and same-wave LDS ops
// complete in program order. Only A->B (cross-wave publish) and C->D
// (cross-wave writeback) barriers are required.
// __launch_bounds__ arg2 = min WORKGROUPS/CU (measured r5); (256,6) -> no spill.
// ---------------------------------------------------------------------------
__global__ __launch_bounds__(256, 6) void roi_kernel10(const uint2* __restrict__ feat,
                                                       const float* __restrict__ rois,
                                                       const int* __restrict__ meta,
                                                       int N, int use_perm,
                                                       float* __restrict__ out) {
  __shared__ float4 smem4[OHW * 32];           // 25088 B, two aliased phases
  float* smem = (float*)smem4;
  const int i = blockIdx.x;
  const int t = threadIdx.x;
  const int g = t & 31;                        // granule within half (4 ch)
  const int r = t >> 5;                        // sample row 0..7

  int n, half;
  if (use_perm) {
    const int p = (i & 7) >> 1;
    half        = i & 1;
    const int s = i >> 3;
    const int c_ = meta[p];
    const int o_ = meta[4 + p];
    const int sl = meta[8 + p];
    const int* perm  = meta + 16;
    const int* extra = meta + 16 + N;
    n = (s < c_) ? perm[o_ + s] : extra[sl + (s - c_)];
  } else {
    n = i >> 1; half = i & 1;
  }

  const float rb = rois[n * 5 + 0];
  const float x1 = FMUL(rois[n * 5 + 1], RSCALE);
  const float y1 = FMUL(rois[n * 5 + 2], RSCALE);
  const float x2 = FMUL(rois[n * 5 + 3], RSCALE);
  const float y2 = FMUL(rois[n * 5 + 4], RSCALE);
  const int   b  = (int)rb;
  const float bh = FDIV(FSUB(y2, y1), 7.0f);
  const float bw = FDIV(FSUB(x2, x1), 7.0f);

  int   xo0[8], xo1[8];
  float lx[8];
  bool  xv[8];
#pragma unroll
  for (int q = 0; q < 8; ++q) {
    const float xs = FADD(x1, FMUL(bw, (float)q));
    xv[q] = (xs >= 0.0f) && (xs < (float)WW);
    const float xf = floorf(xs);
    lx[q] = FSUB(xs, xf);
    int a = (int)xf;
    a = a < 0 ? 0 : (a > WW - 1 ? WW - 1 : a);
    xo0[q] = a * (CCH / 4);
    xo1[q] = ((a + 1 > WW - 1) ? WW - 1 : a + 1) * (CCH / 4);
  }

  const float ys = FADD(y1, FMUL(bh, (float)r));
  const bool  yv = (ys >= 0.0f) && (ys < (float)HH);
  const float yf = floorf(ys);
  const float ly = FSUB(ys, yf);
  int d = (int)yf;
  d = d < 0 ? 0 : (d > HH - 1 ? HH - 1 : d);
  const int d1 = (d + 1 > HH - 1) ? HH - 1 : d + 1;

  const uint2* fb = feat + (size_t)b * (HH * WW) * (CCH / 4) + (half * 32 + g);
  const uint2* r0 = fb + (size_t)d  * (WW * (CCH / 4));
  const uint2* r1 = fb + (size_t)d1 * (WW * (CCH / 4));
  const float wy1 = ly, wy0 = 1.0f - ly;

  float4 hc[7], vprev;
#pragma unroll
  for (int h = 0; h < 2; ++h) {
    uint2 g00[4], g01[4], g10[4], g11[4];
#pragma unroll
    for (int q = 0; q < 4; ++q) {
      const int s = 4 * h + q;
      g00[q] = r0[xo0[s]];
      g01[q] = r0[xo1[s]];
      g10[q] = r1[xo0[s]];
      g11[q] = r1[xo1[s]];
    }
    float4 v[4];
#pragma unroll
    for (int q = 0; q < 4; ++q) {
      const int s = 4 * h + q;
      const bool ok = yv && xv[s];
      const float wx1 = lx[s], wx0 = 1.0f - wx1;
      const float a00 = wy0 * wx0, a01 = wy0 * wx1;
      const float a10 = wy1 * wx0, a11 = wy1 * wx1;
      const float4 f00 = bf4_to_f4(g00[q]);
      const float4 f01 = bf4_to_f4(g01[q]);
      const float4 f10 = bf4_to_f4(g10[q]);
      const float4 f11 = bf4_to_f4(g11[q]);
      float4 rr;
      rr.x = a00 * f00.x + a01 * f01.x + a10 * f10.x + a11 * f11.x;
      rr.y = a00 * f00.y + a01 * f01.y + a10 * f10.y + a11 * f11.y;
      rr.z = a00 * f00.z + a01 * f01.z + a10 * f10.z + a11 * f11.z;
      rr.w = a00 * f00.w + a01 * f01.w + a10 * f10.w + a11 * f11.w;
      v[q] = ok ? rr : make_float4(0.f, 0.f, 0.f, 0.f);
    }
    if (h == 0) {
      hc[0] = f4max(v[0], v[1]);
      hc[1] = f4max(v[1], v[2]);
      hc[2] = f4max(v[2], v[3]);
      vprev = v[3];
    } else {
      hc[3] = f4max(vprev, v[0]);
      hc[4] = f4max(v[0], v[1]);
      hc[5] = f4max(v[1], v[2]);
      hc[6] = f4max(v[2], v[3]);
    }
  }

  // ---- phase A: row r>=1 publishes hc at slot r-1 ----
  if (r >= 1) {
#pragma unroll
    for (int m = 0; m < 7; ++m)
      smem4[((r - 1) * 7 + m) * 32 + g] = hc[m];
  }
  __syncthreads();                             // A->B: cross-wave publish

  // ---- phase B: row r<=6 reads row r+1's hc -> output row r;
  //      phase C: store swizzled (NO barrier needed B->C: same-wave slots) ----
  if (r <= 6) {
#pragma unroll
    for (int m = 0; m < 7; ++m)
      hc[m] = f4max(hc[m], smem4[(r * 7 + m) * 32 + g]);
#pragma unroll
    for (int m = 0; m < 7; ++m) {
      const int s  = r * 7 + m;
      const int gp = g ^ ((s >> 2) & 7);       // XOR swizzle
      smem4[s * 32 + gp] = hc[m];
    }
  }
  __syncthreads();                             // C->D: cross-wave writeback

  // ---- phase D: cached float4 writeback, 1568 float4 over 256 threads ----
  float4* o4 = (float4*)(out + (size_t)n * (CCH * OHW) + half * (CCH / 2) * OHW);
#pragma unroll
  for (int m = 0; m < 7; ++m) {
    const int idx = m * 256 + t;
    if (idx < (CCH / 2) * OHW / 4) {
      const int f0 = idx * 4;
      float4 wv;
      float* wp = (float*)&wv;
#pragma unroll
      for (int k = 0; k < 4; ++k) {
        const int e = f0 + k;
        const int c = e / 49;                  // const divisor -> magic mul
        const int s = e - c * 49;
        wp[k] = smem[s * 128 + 4 * ((c >> 2) ^ ((s >> 2) & 7)) + (c & 3)];
      }
      o4[idx] = wv;
    }
  }
}

// ---------------------------------------------------------------------------
// Fallback (workspace too small): round-2 scalar path, known-correct.
// ---------------------------------------------------------------------------
__global__ __launch_bounds__(256) void roi_kernel_fb(const float* __restrict__ feat,
                                                     const float* __restrict__ rois,
                                                     float* __restrict__ out) {
  __shared__ float sout[CCH * OHW];
  const int n = blockIdx.x;
  const int c = threadIdx.x;

  const float rb = rois[n * 5 + 0];
  const float x1 = FMUL(rois[n * 5 + 1], RSCALE);
  const float y1 = FMUL(rois[n * 5 + 2], RSCALE);
  const float x2 = FMUL(rois[n * 5 + 3], RSCALE);
  const float y2 = FMUL(rois[n * 5 + 4], RSCALE);
  const int b = (int)rb;
  const float bh = FDIV(FSUB(y2, y1), 7.0f);
  const float bw = FDIV(FSUB(x2, x1), 7.0f);

  int ix0[8], ix1[8], iy0[8], iy1[8];
  float lx[8], ly[8];
  bool xv[8], yv[8];
#pragma unroll
  for (int i = 0; i < 8; ++i) {
    const float xs = FADD(x1, FMUL(bw, (float)i));
    const float ys = FADD(y1, FMUL(bh, (float)i));
    xv[i] = (xs >= 0.0f) && (xs < (float)WW);
    yv[i] = (ys >= 0.0f) && (ys < (float)HH);
    const float xf = floorf(xs);
    const float yf = floorf(ys);
    lx[i] = FSUB(xs, xf);
    ly[i] = FSUB(ys, yf);
    int a = (int)xf;
    a = a < 0 ? 0 : (a > WW - 1 ? WW - 1 : a);
    ix0[i] = a;
    ix1[i] = (a + 1 > WW - 1) ? WW - 1 : a + 1;
    int d = (int)yf;
    d = d < 0 ? 0 : (d > HH - 1 ? HH - 1 : d);
    iy0[i] = d;
    iy1[i] = (d + 1 > HH - 1) ? HH - 1 : d + 1;
  }

  const float* fbp = feat + ((size_t)b * CCH + c) * (size_t)(HH * WW);
  float hp[7];
#pragma unroll
  for (int j = 0; j < 8; ++j) {
    float v[8];
    const float wy1 = ly[j], wy0 = 1.0f - ly[j];
#pragma unroll
    for (int i = 0; i < 8; ++i) {
      if (yv[j] && xv[i]) {
        const float f00 = fbp[iy0[j] * WW + ix0[i]];
        const float f01 = fbp[iy0[j] * WW + ix1[i]];
        const float f10 = fbp[iy1[j] * WW + ix0[i]];
        const float f11 = fbp[iy1[j] * WW + ix1[i]];
        const float wx1 = lx[i], wx0 = 1.0f - wx1;
        v[i] = wy0 * (wx0 * f00 + wx1 * f01) + wy1 * (wx0 * f10 + wx1 * f11);
      } else {
        v[i] = 0.0f;
      }
    }
    float hc[7];
#pragma unroll
    for (int i = 0; i < 7; ++i) hc[i] = fmaxf(v[i], v[i + 1]);
    if (j > 0) {
#pragma unroll
      for (int i = 0; i < 7; ++i)
        sout[c * OHW + (j - 1) * 7 + i] = fmaxf(hp[i], hc[i]);
    }
#pragma unroll
    for (int i = 0; i < 7; ++i) hp[i] = hc[i];
  }
  __syncthreads();
  const float4* s4 = (const float4*)sout;
  float4* o4 = (float4*)(out + (size_t)n * (CCH * OHW));
  for (int q = c; q < (CCH * OHW) / 4; q += 256) o4[q] = s4[q];
}

extern "C" void kernel_launch(void* const* d_in, const int* in_sizes, int n_in,
                              void* d_out, int out_size, void* d_ws, size_t ws_size,
                              hipStream_t stream) {
  (void)n_in; (void)out_size;
  const float* feat = (const float*)d_in[0];
  const float* rois = (const float*)d_in[1];
  float* out = (float*)d_out;
  const int N = in_sizes[1] / 5;
  const int B = in_sizes[0] / (CCH * HH * WW);
  const int M = 2 * N;                                  // roi blocks (2/roi)
  const size_t featbf_bytes = (size_t)in_sizes[0] * sizeof(unsigned short);
  const size_t meta_bytes   = (size_t)(16 + 2 * N) * sizeof(int);

  if (ws_size >= featbf_bytes + meta_bytes) {
    unsigned short* featbf = (unsigned short*)d_ws;
    int* meta = (int*)((char*)d_ws + featbf_bytes);
    const int use_perm = (B == 4 && (M & 7) == 0) ? 1 : 0;

    ktrans_sched<<<dim3((HH * WW) / 64, CCH / 64, B + 1), dim3(256), 0, stream>>>(
        feat, featbf, rois, N, M >> 3, use_perm, B, meta);
    roi_kernel10<<<dim3(M), dim3(256), 0, stream>>>(
        (const uint2*)featbf, rois, meta, N, use_perm, out);
  } else {
    roi_kernel_fb<<<dim3(N), dim3(256), 0, stream>>>(feat, rois, out);
  }
}